// Round 1
// baseline (549.072 us; speedup 1.0000x reference)
//
#include <hip/hip_runtime.h>
#include <math.h>

#define NENT 50000
#define RREL 2000
#define AATT 5000
#define EE   400000
#define E2   800000
#define EAE  400000
#define PB   2048   // partials stride per head

__device__ __forceinline__ float leaky(float v){ return v > 0.f ? v : 0.3f * v; }

__device__ __forceinline__ float wave_sum(float v){
#pragma unroll
  for (int m = 32; m; m >>= 1) v += __shfl_xor(v, m);
  return v;
}
__device__ __forceinline__ float wave_max(float v){
#pragma unroll
  for (int m = 32; m; m >>= 1) v = fmaxf(v, __shfl_xor(v, m));
  return v;
}

__device__ int lowb(const int* a, int n, int key){
  int lo = 0, hi = n;
  while (lo < hi){ int mid = (lo + hi) >> 1; if (a[2 * mid] < key) lo = mid + 1; else hi = mid; }
  return lo;
}

// row_ptr build: first index with src >= i, for each of the 3 sorted edge lists
__global__ void k_ptr(const int* ee, const int* er, const int* ea,
                      int* pee, int* per, int* pea){
  int i = blockIdx.x * blockDim.x + threadIdx.x;
  if (i > NENT) return;
  pee[i] = lowb(ee, EE, i);
  per[i] = lowb(er, E2, i);
  pea[i] = lowb(ea, EAE, i);
}

// per-relation / per-attribute scalar tables
__global__ void k_small(const float* rel_emb, const float* attr_emb,
                        const float* w_r, const float* w_a,
                        const float* eaw, const float* caw,
                        float* h_rel, float* h_attr, float* hr, float* hc){
  int t = blockIdx.x * blockDim.x + threadIdx.x;
  if (t < RREL){
    const float* e = rel_emb + (size_t)t * 64;
    float s = 0.f;
    for (int k = 0; k < 64; ++k) s += e[k] * w_r[128 + k];
    h_rel[t] = s;
    for (int lh = 0; lh < 4; ++lh){
      float a = 0.f, c = 0.f;
      for (int k = 0; k < 64; ++k){
        a += e[k] * eaw[lh * 192 + 64 + k];
        c += e[k] * caw[lh * 320 + 128 + k];
      }
      hr[lh * RREL + t] = a;
      hc[lh * RREL + t] = c;
    }
  }
  if (t < AATT){
    const float* e = attr_emb + (size_t)t * 64;
    float s = 0.f;
    for (int k = 0; k < 64; ++k) s += e[k] * w_a[128 + k];
    h_attr[t] = s;
  }
}

// per-entity dot(ent_emb, w[:128]) for both concept score functions; wave per entity
__global__ void k_ent_tab(const float* ent_emb, const float* w_r, const float* w_a,
                          float* her, float* hea){
  int w = (blockIdx.x * blockDim.x + threadIdx.x) >> 6;
  int lane = threadIdx.x & 63;
  if (w >= NENT) return;
  float2 v = ((const float2*)(ent_emb + (size_t)w * 128))[lane];
  float2 a = ((const float2*)w_r)[lane];
  float2 b = ((const float2*)w_a)[lane];
  float sr = v.x * a.x + v.y * a.y;
  float sa = v.x * b.x + v.y * b.y;
  sr = wave_sum(sr);
  sa = wave_sum(sa);
  if (lane == 0){ her[w] = sr; hea[w] = sa; }
}

// GAT concept aggregation (rel or attr); wave per entity, contiguous segment
__global__ void k_concept(const float* h_ent, const float* h_tab, const float* bias_p,
                          const int* idx, const int* ptr, const float* emb,
                          float* out_ent, float* out_conc){
  int w = (blockIdx.x * blockDim.x + threadIdx.x) >> 6;
  int lane = threadIdx.x & 63;
  if (w >= NENT) return;
  int beg = ptr[w], end = ptr[w + 1];
  float he = h_ent[w] + bias_p[0];
  float m = -INFINITY;
  for (int e = beg + lane; e < end; e += 64){
    float a = leaky(he + h_tab[idx[2 * e + 1]]);
    m = fmaxf(m, a);
  }
  m = wave_max(m);
  float z = 0.f;
  for (int e = beg + lane; e < end; e += 64){
    float a = leaky(he + h_tab[idx[2 * e + 1]]);
    z += expf(a - m);
  }
  z = wave_sum(z);
  float acc = 0.f;
  for (int e = beg; e < end; ++e){
    int obj = idx[2 * e + 1];
    float a = leaky(he + h_tab[obj]);
    float pe = expf(a - m) / z;
    acc += pe * emb[(size_t)obj * 64 + lane];
  }
  acc = fmaxf(acc, 0.f);
  out_ent[(size_t)w * 384 + lane] = acc;
  out_conc[(size_t)w * 128 + lane] = acc;
}

// mean neighbor aggregation -> x0 (stored in d_out cols [128:256), stride 384)
__global__ void k_mean(const float* ent_emb, const int* ee, const int* ptr, float* xout){
  int w = (blockIdx.x * blockDim.x + threadIdx.x) >> 6;
  int lane = threadIdx.x & 63;
  if (w >= NENT) return;
  int beg = ptr[w], end = ptr[w + 1];
  float ax = 0.f, ay = 0.f;
  for (int e = beg; e < end; ++e){
    int c = ee[2 * e + 1];
    float2 v = ((const float2*)(ent_emb + (size_t)c * 128))[lane];
    ax += v.x; ay += v.y;
  }
  float d = fmaxf((float)(end - beg), 1.f);
  xout[(size_t)w * 384 + 2 * lane]     = ax / d;
  xout[(size_t)w * 384 + 2 * lane + 1] = ay / d;
}

// con-attention per-entity tables A (row side), B (col side) for all 4 (l,h)
__global__ void k_AB(const float* out, const float* caw, float* Acon, float* Bcon){
  int w = (blockIdx.x * blockDim.x + threadIdx.x) >> 6;
  int lane = threadIdx.x & 63;
  if (w >= NENT) return;
  float cr = out[(size_t)w * 384 + 256 + lane];
  float cv = out[(size_t)w * 384 + 320 + lane];
  for (int lh = 0; lh < 4; ++lh){
    const float* cw = caw + lh * 320;
    float av = cr * cw[lane]       + cv * cw[64 + lane];
    float bv = cr * cw[192 + lane] + cv * cw[256 + lane];
    av = wave_sum(av);
    bv = wave_sum(bv);
    if (lane == 0){ Acon[lh * NENT + w] = av; Bcon[lh * NENT + w] = bv; }
  }
}

// per-entity u1/v1 for both heads of one layer (relu applied on read)
__global__ void k_uv(const float* xsrc, const float* eaw_l, float* u1, float* v1){
  int w = (blockIdx.x * blockDim.x + threadIdx.x) >> 6;
  int lane = threadIdx.x & 63;
  if (w >= NENT) return;
  float x0 = fmaxf(xsrc[(size_t)w * 384 + lane], 0.f);
  float x1 = fmaxf(xsrc[(size_t)w * 384 + 64 + lane], 0.f);
  for (int h = 0; h < 2; ++h){
    const float* wv = eaw_l + h * 192;
    float xv = h ? x1 : x0;
    float u = xv * wv[lane];
    float v = xv * wv[128 + lane];
    u = wave_sum(u);
    v = wave_sum(v);
    if (lane == 0){ u1[h * NENT + w] = u; v1[h * NENT + w] = v; }
  }
}

// edge scores s = leaky(ea)*leaky(ca) for both heads + deterministic block max
__global__ void k_s(const int* ee, const int* err,
                    const float* u1, const float* v1,
                    const float* Acon_l, const float* Bcon_l,
                    const float* hr_l, const float* hc_l,
                    const float* eab_l, const float* cab_l,
                    float* s0, float* s1, float* partials){
  int e = blockIdx.x * blockDim.x + threadIdx.x;
  int tid = threadIdx.x;
  __shared__ float sm[256];
  float m0 = -INFINITY, m1 = -INFINITY;
  if (e < EE){
    int row = ee[2 * e], col = ee[2 * e + 1];
    int r1 = err[2 * e], r2 = err[2 * e + 1];
    {
      float eav = leaky(u1[row] + 0.5f * (hr_l[r1] + hr_l[r2]) + v1[col] + eab_l[0]);
      float cav = leaky(Acon_l[row] + 0.5f * (hc_l[r1] + hc_l[r2]) + Bcon_l[col] + cab_l[0]);
      float sv = eav * cav;
      s0[e] = sv; m0 = sv;
    }
    {
      float eav = leaky(u1[NENT + row] + 0.5f * (hr_l[RREL + r1] + hr_l[RREL + r2]) + v1[NENT + col] + eab_l[1]);
      float cav = leaky(Acon_l[NENT + row] + 0.5f * (hc_l[RREL + r1] + hc_l[RREL + r2]) + Bcon_l[NENT + col] + cab_l[1]);
      float sv = eav * cav;
      s1[e] = sv; m1 = sv;
    }
  }
  sm[tid] = m0; __syncthreads();
  for (int s = 128; s; s >>= 1){
    if (tid < s) sm[tid] = fmaxf(sm[tid], sm[tid + s]);
    __syncthreads();
  }
  if (tid == 0) partials[blockIdx.x] = sm[0];
  __syncthreads();
  sm[tid] = m1; __syncthreads();
  for (int s = 128; s; s >>= 1){
    if (tid < s) sm[tid] = fmaxf(sm[tid], sm[tid + s]);
    __syncthreads();
  }
  if (tid == 0) partials[PB + blockIdx.x] = sm[0];
}

// sum of exp(s - M) per block, deterministic
__global__ void k_expsum(const float* s0, const float* s1, const float* scal, float* partials){
  int e = blockIdx.x * blockDim.x + threadIdx.x;
  int tid = threadIdx.x;
  __shared__ float sm[256];
  float v0 = 0.f, v1 = 0.f;
  if (e < EE){
    v0 = expf(s0[e] - scal[0]);
    v1 = expf(s1[e] - scal[1]);
  }
  sm[tid] = v0; __syncthreads();
  for (int s = 128; s; s >>= 1){
    if (tid < s) sm[tid] += sm[tid + s];
    __syncthreads();
  }
  if (tid == 0) partials[blockIdx.x] = sm[0];
  __syncthreads();
  sm[tid] = v1; __syncthreads();
  for (int s = 128; s; s >>= 1){
    if (tid < s) sm[tid] += sm[tid + s];
    __syncthreads();
  }
  if (tid == 0) partials[PB + blockIdx.x] = sm[0];
}

// single-block finalize: op=0 max -> scal[h], op=1 sum -> scal[2+h]
__global__ void k_final(const float* partials, float* scal, int nb, int op){
  __shared__ float sm[1024];
  int tid = threadIdx.x;
  for (int h = 0; h < 2; ++h){
    float v = op ? 0.f : -INFINITY;
    for (int i = tid; i < nb; i += 1024){
      float x = partials[h * PB + i];
      v = op ? (v + x) : fmaxf(v, x);
    }
    sm[tid] = v; __syncthreads();
    for (int s = 512; s; s >>= 1){
      if (tid < s) sm[tid] = op ? (sm[tid] + sm[tid + s]) : fmaxf(sm[tid], sm[tid + s]);
      __syncthreads();
    }
    if (tid == 0) scal[op * 2 + h] = sm[0];
    __syncthreads();
  }
}

// global softmax -> segment softmax -> weighted neighbor sum -> tanh
// wave per (entity, head); writes d_out cols [l*128 + h*64, +64)
__global__ void k_agg(const int* ee, const int* ptr, const float* s0, const float* s1,
                      const float* scal, const float* xsrc, float* outp){
  int w = (blockIdx.x * blockDim.x + threadIdx.x) >> 6;
  int lane = threadIdx.x & 63;
  if (w >= 2 * NENT) return;
  int i = w >> 1, h = w & 1;
  int beg = ptr[i], end = ptr[i + 1];
  const float* sh = h ? s1 : s0;
  float M = scal[h], Z = scal[2 + h];
  float m2 = -INFINITY;
  for (int e = beg + lane; e < end; e += 64)
    m2 = fmaxf(m2, expf(sh[e] - M) / Z);
  m2 = wave_max(m2);
  float z2 = 0.f;
  for (int e = beg + lane; e < end; e += 64)
    z2 += expf(expf(sh[e] - M) / Z - m2);
  z2 = wave_sum(z2);
  float acc = 0.f;
  for (int e = beg; e < end; ++e){
    float pe = expf(sh[e] - M) / Z;
    float ph = expf(pe - m2) / z2;
    int c = ee[2 * e + 1];
    float xv = fmaxf(xsrc[(size_t)c * 384 + h * 64 + lane], 0.f);
    acc += ph * xv;
  }
  outp[(size_t)i * 384 + h * 64 + lane] = tanhf(acc);
}

extern "C" void kernel_launch(void* const* d_in, const int* in_sizes, int n_in,
                              void* d_out, int out_size, void* d_ws, size_t ws_size,
                              hipStream_t stream){
  const float* ent_emb  = (const float*)d_in[0];
  const float* rel_emb  = (const float*)d_in[1];
  const float* attr_emb = (const float*)d_in[2];
  const float* w_r      = (const float*)d_in[3];
  const float* b_r      = (const float*)d_in[4];
  const float* w_a      = (const float*)d_in[5];
  const float* b_a      = (const float*)d_in[6];
  const float* eaw      = (const float*)d_in[7];
  const float* eab      = (const float*)d_in[8];
  const float* caw      = (const float*)d_in[9];
  const float* cab      = (const float*)d_in[10];
  const int*   ee       = (const int*)d_in[11];
  const int*   er_rel   = (const int*)d_in[13];
  const int*   er_idx   = (const int*)d_in[14];
  const int*   ea_idx   = (const int*)d_in[15];
  float* out = (float*)d_out;

  // workspace carve (all fp32/int32, ~7 MB)
  int* pee = (int*)d_ws;
  int* per = pee + (NENT + 1);
  int* pea = per + (NENT + 1);
  float* fb      = (float*)(pea + (NENT + 1) + 1);
  float* s0      = fb;
  float* s1      = s0 + EE;
  float* her     = s1 + EE;
  float* hea     = her + NENT;
  float* h_rel   = hea + NENT;
  float* h_attr  = h_rel + RREL;
  float* hr      = h_attr + AATT;
  float* hc      = hr + 4 * RREL;
  float* Acon    = hc + 4 * RREL;
  float* Bcon    = Acon + 4 * NENT;
  float* u1      = Bcon + 4 * NENT;
  float* v1      = u1 + 2 * NENT;
  float* partials= v1 + 2 * NENT;
  float* scal    = partials + 2 * PB;

  const int nb = (EE + 255) / 256;          // edge-grid blocks (1563)
  const int gw = (NENT + 3) / 4;            // wave-per-entity grids (4 waves/block)

  k_ptr<<<(NENT + 1 + 255) / 256, 256, 0, stream>>>(ee, er_idx, ea_idx, pee, per, pea);
  k_small<<<(AATT + 255) / 256, 256, 0, stream>>>(rel_emb, attr_emb, w_r, w_a, eaw, caw,
                                                  h_rel, h_attr, hr, hc);
  k_ent_tab<<<gw, 256, 0, stream>>>(ent_emb, w_r, w_a, her, hea);
  // concept_rel -> ent_out cols [256:320) and conc cols [0:64)
  k_concept<<<gw, 256, 0, stream>>>(her, h_rel, b_r, er_idx, per, rel_emb,
                                    out + 256, out + (size_t)NENT * 384);
  // concept_attr -> ent_out cols [320:384) and conc cols [64:128)
  k_concept<<<gw, 256, 0, stream>>>(hea, h_attr, b_a, ea_idx, pea, attr_emb,
                                    out + 320, out + (size_t)NENT * 384 + 64);
  // x0 (mean agg) temporarily in ent_out cols [128:256)
  k_mean<<<gw, 256, 0, stream>>>(ent_emb, ee, pee, out + 128);
  k_AB<<<gw, 256, 0, stream>>>(out, caw, Acon, Bcon);

  for (int l = 0; l < 2; ++l){
    const float* xsrc = (l == 0) ? (out + 128) : out;  // layer0 reads x0, layer1 reads layer0 out
    k_uv<<<gw, 256, 0, stream>>>(xsrc, eaw + l * 2 * 192, u1, v1);
    k_s<<<nb, 256, 0, stream>>>(ee, er_rel, u1, v1,
                                Acon + l * 2 * NENT, Bcon + l * 2 * NENT,
                                hr + l * 2 * RREL, hc + l * 2 * RREL,
                                eab + l * 2, cab + l * 2, s0, s1, partials);
    k_final<<<1, 1024, 0, stream>>>(partials, scal, nb, 0);
    k_expsum<<<nb, 256, 0, stream>>>(s0, s1, scal, partials);
    k_final<<<1, 1024, 0, stream>>>(partials, scal, nb, 1);
    k_agg<<<(2 * NENT + 3) / 4, 256, 0, stream>>>(ee, pee, s0, s1, scal, xsrc, out + l * 128);
  }
}

// Round 2
// 421.534 us; speedup vs baseline: 1.3026x; 1.3026x over previous
//
#include <hip/hip_runtime.h>
#include <math.h>

#define NENT 50000
#define RREL 2000
#define AATT 5000
#define EE   400000
#define E2   800000
#define EAE  400000
#define PB   2048   // partials stride per head

__device__ __forceinline__ float leaky(float v){ return v > 0.f ? v : 0.3f * v; }

__device__ __forceinline__ float wave_sum(float v){
#pragma unroll
  for (int m = 32; m; m >>= 1) v += __shfl_xor(v, m);
  return v;
}
__device__ __forceinline__ float wave_max(float v){
#pragma unroll
  for (int m = 32; m; m >>= 1) v = fmaxf(v, __shfl_xor(v, m));
  return v;
}

__device__ int lowb(const int* a, int n, int key){
  int lo = 0, hi = n;
  while (lo < hi){ int mid = (lo + hi) >> 1; if (a[2 * mid] < key) lo = mid + 1; else hi = mid; }
  return lo;
}

// row_ptr build: first index with src >= i, for each of the 3 sorted edge lists
__global__ void k_ptr(const int* ee, const int* er, const int* ea,
                      int* pee, int* per, int* pea){
  int i = blockIdx.x * blockDim.x + threadIdx.x;
  if (i > NENT) return;
  pee[i] = lowb(ee, EE, i);
  per[i] = lowb(er, E2, i);
  pea[i] = lowb(ea, EAE, i);
}

// per-relation / per-attribute scalar tables
__global__ void k_small(const float* rel_emb, const float* attr_emb,
                        const float* w_r, const float* w_a,
                        const float* eaw, const float* caw,
                        float* h_rel, float* h_attr, float* hr, float* hc){
  int t = blockIdx.x * blockDim.x + threadIdx.x;
  if (t < RREL){
    const float* e = rel_emb + (size_t)t * 64;
    float s = 0.f;
    for (int k = 0; k < 64; ++k) s += e[k] * w_r[128 + k];
    h_rel[t] = s;
    for (int lh = 0; lh < 4; ++lh){
      float a = 0.f, c = 0.f;
      for (int k = 0; k < 64; ++k){
        a += e[k] * eaw[lh * 192 + 64 + k];
        c += e[k] * caw[lh * 320 + 128 + k];
      }
      hr[lh * RREL + t] = a;
      hc[lh * RREL + t] = c;
    }
  }
  if (t < AATT){
    const float* e = attr_emb + (size_t)t * 64;
    float s = 0.f;
    for (int k = 0; k < 64; ++k) s += e[k] * w_a[128 + k];
    h_attr[t] = s;
  }
}

// per-entity dot(ent_emb, w[:128]) for both concept score functions; wave per entity
__global__ void k_ent_tab(const float* ent_emb, const float* w_r, const float* w_a,
                          float* her, float* hea){
  int w = (blockIdx.x * blockDim.x + threadIdx.x) >> 6;
  int lane = threadIdx.x & 63;
  if (w >= NENT) return;
  float2 v = ((const float2*)(ent_emb + (size_t)w * 128))[lane];
  float2 a = ((const float2*)w_r)[lane];
  float2 b = ((const float2*)w_a)[lane];
  float sr = v.x * a.x + v.y * a.y;
  float sa = v.x * b.x + v.y * b.y;
  sr = wave_sum(sr);
  sa = wave_sum(sa);
  if (lane == 0){ her[w] = sr; hea[w] = sa; }
}

// GAT concept aggregation (rel or attr); wave per entity, contiguous segment.
// Weights computed wave-strided (1 exp/edge across the wave), then shfl-broadcast
// while each lane owns one feature dim of the gathered embedding row.
__global__ void k_concept(const float* h_ent, const float* h_tab, const float* bias_p,
                          const int* idx, const int* ptr, const float* emb,
                          float* out_ent, float* out_conc){
  int w = (blockIdx.x * blockDim.x + threadIdx.x) >> 6;
  int lane = threadIdx.x & 63;
  if (w >= NENT) return;
  int beg = ptr[w], end = ptr[w + 1];
  float he = h_ent[w] + bias_p[0];
  float m = -INFINITY;
  for (int e = beg + lane; e < end; e += 64)
    m = fmaxf(m, leaky(he + h_tab[idx[2 * e + 1]]));
  m = wave_max(m);
  float z = 0.f;
  for (int e = beg + lane; e < end; e += 64)
    z += __expf(leaky(he + h_tab[idx[2 * e + 1]]) - m);
  z = wave_sum(z);
  float invz = (z > 0.f) ? (1.f / z) : 0.f;
  float acc = 0.f;
  for (int e0 = beg; e0 < end; e0 += 64){
    int e = e0 + lane;
    float wgt = 0.f; int obj = 0;
    if (e < end){
      obj = idx[2 * e + 1];
      wgt = __expf(leaky(he + h_tab[obj]) - m) * invz;
    }
    int cnt = end - e0; if (cnt > 64) cnt = 64;
    for (int j = 0; j < cnt; ++j){
      float wj = __shfl(wgt, j);
      int oj   = __shfl(obj, j);
      acc = fmaf(wj, emb[(size_t)oj * 64 + lane], acc);
    }
  }
  acc = fmaxf(acc, 0.f);
  out_ent[(size_t)w * 384 + lane] = acc;
  out_conc[(size_t)w * 128 + lane] = acc;
}

// mean neighbor aggregation -> x0 (stored in d_out cols [128:256), stride 384)
__global__ void k_mean(const float* ent_emb, const int* ee, const int* ptr, float* xout){
  int w = (blockIdx.x * blockDim.x + threadIdx.x) >> 6;
  int lane = threadIdx.x & 63;
  if (w >= NENT) return;
  int beg = ptr[w], end = ptr[w + 1];
  float ax = 0.f, ay = 0.f;
  for (int e0 = beg; e0 < end; e0 += 64){
    int e = e0 + lane;
    int col = (e < end) ? ee[2 * e + 1] : 0;
    int cnt = end - e0; if (cnt > 64) cnt = 64;
    for (int j = 0; j < cnt; ++j){
      int cj = __shfl(col, j);
      float2 v = ((const float2*)(ent_emb + (size_t)cj * 128))[lane];
      ax += v.x; ay += v.y;
    }
  }
  float d = fmaxf((float)(end - beg), 1.f);
  float invd = 1.f / d;
  xout[(size_t)w * 384 + 2 * lane]     = ax * invd;
  xout[(size_t)w * 384 + 2 * lane + 1] = ay * invd;
}

// con-attention per-entity tables A (row side), B (col side) for all 4 (l,h)
__global__ void k_AB(const float* out, const float* caw, float* Acon, float* Bcon){
  int w = (blockIdx.x * blockDim.x + threadIdx.x) >> 6;
  int lane = threadIdx.x & 63;
  if (w >= NENT) return;
  float cr = out[(size_t)w * 384 + 256 + lane];
  float cv = out[(size_t)w * 384 + 320 + lane];
  for (int lh = 0; lh < 4; ++lh){
    const float* cw = caw + lh * 320;
    float av = cr * cw[lane]       + cv * cw[64 + lane];
    float bv = cr * cw[192 + lane] + cv * cw[256 + lane];
    av = wave_sum(av);
    bv = wave_sum(bv);
    if (lane == 0){ Acon[lh * NENT + w] = av; Bcon[lh * NENT + w] = bv; }
  }
}

// per-entity u1/v1 for both heads of one layer (relu applied on read)
__global__ void k_uv(const float* xsrc, const float* eaw_l, float* u1, float* v1){
  int w = (blockIdx.x * blockDim.x + threadIdx.x) >> 6;
  int lane = threadIdx.x & 63;
  if (w >= NENT) return;
  float x0 = fmaxf(xsrc[(size_t)w * 384 + lane], 0.f);
  float x1 = fmaxf(xsrc[(size_t)w * 384 + 64 + lane], 0.f);
  for (int h = 0; h < 2; ++h){
    const float* wv = eaw_l + h * 192;
    float xv = h ? x1 : x0;
    float u = xv * wv[lane];
    float v = xv * wv[128 + lane];
    u = wave_sum(u);
    v = wave_sum(v);
    if (lane == 0){ u1[h * NENT + w] = u; v1[h * NENT + w] = v; }
  }
}

// edge scores s = leaky(ea)*leaky(ca) for both heads + deterministic block max
__global__ void k_s(const int* ee, const int* err,
                    const float* u1, const float* v1,
                    const float* Acon_l, const float* Bcon_l,
                    const float* hr_l, const float* hc_l,
                    const float* eab_l, const float* cab_l,
                    float* s0, float* s1, float* partials){
  int e = blockIdx.x * blockDim.x + threadIdx.x;
  int tid = threadIdx.x;
  __shared__ float sm[256];
  float m0 = -INFINITY, m1 = -INFINITY;
  if (e < EE){
    int row = ee[2 * e], col = ee[2 * e + 1];
    int r1 = err[2 * e], r2 = err[2 * e + 1];
    {
      float eav = leaky(u1[row] + 0.5f * (hr_l[r1] + hr_l[r2]) + v1[col] + eab_l[0]);
      float cav = leaky(Acon_l[row] + 0.5f * (hc_l[r1] + hc_l[r2]) + Bcon_l[col] + cab_l[0]);
      float sv = eav * cav;
      s0[e] = sv; m0 = sv;
    }
    {
      float eav = leaky(u1[NENT + row] + 0.5f * (hr_l[RREL + r1] + hr_l[RREL + r2]) + v1[NENT + col] + eab_l[1]);
      float cav = leaky(Acon_l[NENT + row] + 0.5f * (hc_l[RREL + r1] + hc_l[RREL + r2]) + Bcon_l[NENT + col] + cab_l[1]);
      float sv = eav * cav;
      s1[e] = sv; m1 = sv;
    }
  }
  sm[tid] = m0; __syncthreads();
  for (int s = 128; s; s >>= 1){
    if (tid < s) sm[tid] = fmaxf(sm[tid], sm[tid + s]);
    __syncthreads();
  }
  if (tid == 0) partials[blockIdx.x] = sm[0];
  __syncthreads();
  sm[tid] = m1; __syncthreads();
  for (int s = 128; s; s >>= 1){
    if (tid < s) sm[tid] = fmaxf(sm[tid], sm[tid + s]);
    __syncthreads();
  }
  if (tid == 0) partials[PB + blockIdx.x] = sm[0];
}

// exp(s - M): store back in-place (first-level softmax numerator) + block sums
__global__ void k_expsum(float* s0, float* s1, const float* scal, float* partials){
  int e = blockIdx.x * blockDim.x + threadIdx.x;
  int tid = threadIdx.x;
  __shared__ float sm[256];
  float v0 = 0.f, v1 = 0.f;
  if (e < EE){
    v0 = __expf(s0[e] - scal[0]);
    v1 = __expf(s1[e] - scal[1]);
    s0[e] = v0;
    s1[e] = v1;
  }
  sm[tid] = v0; __syncthreads();
  for (int s = 128; s; s >>= 1){
    if (tid < s) sm[tid] += sm[tid + s];
    __syncthreads();
  }
  if (tid == 0) partials[blockIdx.x] = sm[0];
  __syncthreads();
  sm[tid] = v1; __syncthreads();
  for (int s = 128; s; s >>= 1){
    if (tid < s) sm[tid] += sm[tid + s];
    __syncthreads();
  }
  if (tid == 0) partials[PB + blockIdx.x] = sm[0];
}

// single-block finalize: op=0 max -> scal[h], op=1 sum -> scal[2+h]
__global__ void k_final(const float* partials, float* scal, int nb, int op){
  __shared__ float sm[1024];
  int tid = threadIdx.x;
  for (int h = 0; h < 2; ++h){
    float v = op ? 0.f : -INFINITY;
    for (int i = tid; i < nb; i += 1024){
      float x = partials[h * PB + i];
      v = op ? (v + x) : fmaxf(v, x);
    }
    sm[tid] = v; __syncthreads();
    for (int s = 512; s; s >>= 1){
      if (tid < s) sm[tid] = op ? (sm[tid] + sm[tid + s]) : fmaxf(sm[tid], sm[tid + s]);
      __syncthreads();
    }
    if (tid == 0) scal[op * 2 + h] = sm[0];
    __syncthreads();
  }
}

// second-level (segment) softmax over p = e'/Z, then weighted neighbor sum, tanh.
// s0/s1 now hold e' = exp(s - M). Wave per (entity, head); weights computed
// wave-strided then shfl-broadcast during the gather-accumulate.
__global__ void k_agg(const int* ee, const int* ptr, const float* s0, const float* s1,
                      const float* scal, const float* xsrc, float* outp){
  int w = (blockIdx.x * blockDim.x + threadIdx.x) >> 6;
  int lane = threadIdx.x & 63;
  if (w >= 2 * NENT) return;
  int i = w >> 1, h = w & 1;
  int beg = ptr[i], end = ptr[i + 1];
  const float* sh = h ? s1 : s0;
  float invZ = 1.f / scal[2 + h];
  float m2 = -INFINITY;
  for (int e = beg + lane; e < end; e += 64)
    m2 = fmaxf(m2, sh[e] * invZ);
  m2 = wave_max(m2);
  float z2 = 0.f;
  for (int e = beg + lane; e < end; e += 64)
    z2 += __expf(sh[e] * invZ - m2);
  z2 = wave_sum(z2);
  float invz2 = (z2 > 0.f) ? (1.f / z2) : 0.f;
  float acc = 0.f;
  for (int e0 = beg; e0 < end; e0 += 64){
    int e = e0 + lane;
    float wgt = 0.f; int col = 0;
    if (e < end){
      col = ee[2 * e + 1];
      wgt = __expf(sh[e] * invZ - m2) * invz2;
    }
    int cnt = end - e0; if (cnt > 64) cnt = 64;
    for (int j = 0; j < cnt; ++j){
      float wj = __shfl(wgt, j);
      int cj   = __shfl(col, j);
      float xv = fmaxf(xsrc[(size_t)cj * 384 + h * 64 + lane], 0.f);
      acc = fmaf(wj, xv, acc);
    }
  }
  outp[(size_t)i * 384 + h * 64 + lane] = tanhf(acc);
}

extern "C" void kernel_launch(void* const* d_in, const int* in_sizes, int n_in,
                              void* d_out, int out_size, void* d_ws, size_t ws_size,
                              hipStream_t stream){
  const float* ent_emb  = (const float*)d_in[0];
  const float* rel_emb  = (const float*)d_in[1];
  const float* attr_emb = (const float*)d_in[2];
  const float* w_r      = (const float*)d_in[3];
  const float* b_r      = (const float*)d_in[4];
  const float* w_a      = (const float*)d_in[5];
  const float* b_a      = (const float*)d_in[6];
  const float* eaw      = (const float*)d_in[7];
  const float* eab      = (const float*)d_in[8];
  const float* caw      = (const float*)d_in[9];
  const float* cab      = (const float*)d_in[10];
  const int*   ee       = (const int*)d_in[11];
  const int*   er_rel   = (const int*)d_in[13];
  const int*   er_idx   = (const int*)d_in[14];
  const int*   ea_idx   = (const int*)d_in[15];
  float* out = (float*)d_out;

  // workspace carve (all fp32/int32, ~7 MB)
  int* pee = (int*)d_ws;
  int* per = pee + (NENT + 1);
  int* pea = per + (NENT + 1);
  float* fb      = (float*)(pea + (NENT + 1) + 1);
  float* s0      = fb;
  float* s1      = s0 + EE;
  float* her     = s1 + EE;
  float* hea     = her + NENT;
  float* h_rel   = hea + NENT;
  float* h_attr  = h_rel + RREL;
  float* hr      = h_attr + AATT;
  float* hc      = hr + 4 * RREL;
  float* Acon    = hc + 4 * RREL;
  float* Bcon    = Acon + 4 * NENT;
  float* u1      = Bcon + 4 * NENT;
  float* v1      = u1 + 2 * NENT;
  float* partials= v1 + 2 * NENT;
  float* scal    = partials + 2 * PB;

  const int nb = (EE + 255) / 256;          // edge-grid blocks (1563)
  const int gw = (NENT + 3) / 4;            // wave-per-entity grids (4 waves/block)

  k_ptr<<<(NENT + 1 + 255) / 256, 256, 0, stream>>>(ee, er_idx, ea_idx, pee, per, pea);
  k_small<<<(AATT + 255) / 256, 256, 0, stream>>>(rel_emb, attr_emb, w_r, w_a, eaw, caw,
                                                  h_rel, h_attr, hr, hc);
  k_ent_tab<<<gw, 256, 0, stream>>>(ent_emb, w_r, w_a, her, hea);
  // concept_rel -> ent_out cols [256:320) and conc cols [0:64)
  k_concept<<<gw, 256, 0, stream>>>(her, h_rel, b_r, er_idx, per, rel_emb,
                                    out + 256, out + (size_t)NENT * 384);
  // concept_attr -> ent_out cols [320:384) and conc cols [64:128)
  k_concept<<<gw, 256, 0, stream>>>(hea, h_attr, b_a, ea_idx, pea, attr_emb,
                                    out + 320, out + (size_t)NENT * 384 + 64);
  // x0 (mean agg) temporarily in ent_out cols [128:256)
  k_mean<<<gw, 256, 0, stream>>>(ent_emb, ee, pee, out + 128);
  k_AB<<<gw, 256, 0, stream>>>(out, caw, Acon, Bcon);

  for (int l = 0; l < 2; ++l){
    const float* xsrc = (l == 0) ? (out + 128) : out;  // layer0 reads x0, layer1 reads layer0 out
    k_uv<<<gw, 256, 0, stream>>>(xsrc, eaw + l * 2 * 192, u1, v1);
    k_s<<<nb, 256, 0, stream>>>(ee, er_rel, u1, v1,
                                Acon + l * 2 * NENT, Bcon + l * 2 * NENT,
                                hr + l * 2 * RREL, hc + l * 2 * RREL,
                                eab + l * 2, cab + l * 2, s0, s1, partials);
    k_final<<<1, 1024, 0, stream>>>(partials, scal, nb, 0);
    k_expsum<<<nb, 256, 0, stream>>>(s0, s1, scal, partials);
    k_final<<<1, 1024, 0, stream>>>(partials, scal, nb, 1);
    k_agg<<<(2 * NENT + 3) / 4, 256, 0, stream>>>(ee, pee, s0, s1, scal, xsrc, out + l * 128);
  }
}

// Round 3
// 306.269 us; speedup vs baseline: 1.7928x; 1.3764x over previous
//
#include <hip/hip_runtime.h>
#include <math.h>

#define NENT 50000
#define RREL 2000
#define AATT 5000
#define EE   400000
#define E2   800000
#define EAE  400000
#define PB   2048   // partials stride per head

__device__ __forceinline__ float leaky(float v){ return v > 0.f ? v : 0.3f * v; }

__device__ __forceinline__ float wave_sum(float v){
#pragma unroll
  for (int m = 32; m; m >>= 1) v += __shfl_xor(v, m);
  return v;
}
__device__ __forceinline__ float wave_max(float v){
#pragma unroll
  for (int m = 32; m; m >>= 1) v = fmaxf(v, __shfl_xor(v, m));
  return v;
}
// reduces independently within each 32-lane half (xor masks < 32 never cross bit 5)
__device__ __forceinline__ float half_sum(float v){
#pragma unroll
  for (int m = 16; m; m >>= 1) v += __shfl_xor(v, m);
  return v;
}

__device__ int lowb(const int* a, int n, int key){
  int lo = 0, hi = n;
  while (lo < hi){ int mid = (lo + hi) >> 1; if (a[2 * mid] < key) lo = mid + 1; else hi = mid; }
  return lo;
}

__global__ void k_ptr(const int* ee, const int* er, const int* ea,
                      int* pee, int* per, int* pea){
  int i = blockIdx.x * blockDim.x + threadIdx.x;
  if (i > NENT) return;
  pee[i] = lowb(ee, EE, i);
  per[i] = lowb(er, E2, i);
  pea[i] = lowb(ea, EAE, i);
}

// per-relation/attr scalar tables; HH_l[r] = (hr_h0, hr_h1, hc_h0, hc_h1)
__global__ void k_small(const float* rel_emb, const float* attr_emb,
                        const float* w_r, const float* w_a,
                        const float* eaw, const float* caw,
                        float* h_rel, float* h_attr, float4* HH0, float4* HH1){
  int t = blockIdx.x * blockDim.x + threadIdx.x;
  if (t < RREL){
    const float* e = rel_emb + (size_t)t * 64;
    float s = 0.f;
    for (int k = 0; k < 64; ++k) s += e[k] * w_r[128 + k];
    h_rel[t] = s;
    float hr[4], hc[4];
    for (int lh = 0; lh < 4; ++lh){
      float a = 0.f, c = 0.f;
      for (int k = 0; k < 64; ++k){
        a += e[k] * eaw[lh * 192 + 64 + k];
        c += e[k] * caw[lh * 320 + 128 + k];
      }
      hr[lh] = a; hc[lh] = c;
    }
    HH0[t] = make_float4(hr[0], hr[1], hc[0], hc[1]);
    HH1[t] = make_float4(hr[2], hr[3], hc[2], hc[3]);
  }
  if (t < AATT){
    const float* e = attr_emb + (size_t)t * 64;
    float s = 0.f;
    for (int k = 0; k < 64; ++k) s += e[k] * w_a[128 + k];
    h_attr[t] = s;
  }
}

__device__ float concept_agg(float he, const float* h_tab, const int* idx,
                             int beg, int end, const float* emb, int lane){
  float m = -INFINITY;
  for (int e = beg + lane; e < end; e += 64)
    m = fmaxf(m, leaky(he + h_tab[idx[2 * e + 1]]));
  m = wave_max(m);
  float z = 0.f;
  for (int e = beg + lane; e < end; e += 64)
    z += __expf(leaky(he + h_tab[idx[2 * e + 1]]) - m);
  z = wave_sum(z);
  float invz = (z > 0.f) ? (1.f / z) : 0.f;
  float acc = 0.f;
  for (int e0 = beg; e0 < end; e0 += 64){
    int e = e0 + lane;
    float wgt = 0.f; int obj = 0;
    if (e < end){
      obj = idx[2 * e + 1];
      wgt = __expf(leaky(he + h_tab[obj]) - m) * invz;
    }
    int cnt = end - e0; if (cnt > 64) cnt = 64;
    for (int j = 0; j < cnt; ++j){
      float wj = __shfl(wgt, j);
      int oj   = __shfl(obj, j);
      acc = fmaf(wj, emb[(size_t)oj * 64 + lane], acc);
    }
  }
  return fmaxf(acc, 0.f);
}

// all row-local per-entity work fused: ent dot tables, both concept GATs,
// mean aggregation, con-attention A/B tables (4 lh), layer-0 u/v tables.
__global__ void k_phase1(const float* ent_emb, const float* rel_emb, const float* attr_emb,
                         const float* w_r, const float* b_r, const float* w_a, const float* b_a,
                         const float* eaw, const float* caw,
                         const int* er_idx, const int* ea_idx, const int* ee,
                         const int* per, const int* pea, const int* pee,
                         const float* h_rel, const float* h_attr,
                         float4* UA0, float4* VB0, float4* UA1, float4* VB1,
                         float* out){
  int w = (blockIdx.x * blockDim.x + threadIdx.x) >> 6;
  int lane = threadIdx.x & 63;
  if (w >= NENT) return;
  // her / hea (dot of own ent row with w_r/w_a first 128)
  float2 v = ((const float2*)(ent_emb + (size_t)w * 128))[lane];
  float2 a = ((const float2*)w_r)[lane];
  float2 b = ((const float2*)w_a)[lane];
  float her = wave_sum(v.x * a.x + v.y * a.y);
  float hea = wave_sum(v.x * b.x + v.y * b.y);
  // concept aggregations
  float accR = concept_agg(her + b_r[0], h_rel, er_idx, per[w], per[w + 1], rel_emb, lane);
  float accA = concept_agg(hea + b_a[0], h_attr, ea_idx, pea[w], pea[w + 1], attr_emb, lane);
  out[(size_t)w * 384 + 256 + lane] = accR;
  out[(size_t)w * 384 + 320 + lane] = accA;
  out[(size_t)NENT * 384 + (size_t)w * 128 + lane] = accR;
  out[(size_t)NENT * 384 + (size_t)w * 128 + 64 + lane] = accA;
  // mean neighbor aggregation -> x0 (out cols [128:256))
  int beg = pee[w], end = pee[w + 1];
  float ax = 0.f, ay = 0.f;
  for (int e0 = beg; e0 < end; e0 += 64){
    int e = e0 + lane;
    int col = (e < end) ? ee[2 * e + 1] : 0;
    int cnt = end - e0; if (cnt > 64) cnt = 64;
    for (int j = 0; j < cnt; ++j){
      int cj = __shfl(col, j);
      float2 vv = ((const float2*)(ent_emb + (size_t)cj * 128))[lane];
      ax += vv.x; ay += vv.y;
    }
  }
  float invd = 1.f / fmaxf((float)(end - beg), 1.f);
  ax *= invd; ay *= invd;
  out[(size_t)w * 384 + 128 + 2 * lane]     = ax;
  out[(size_t)w * 384 + 128 + 2 * lane + 1] = ay;
  // con-attention tables A (row) / B (col) for all 4 (l,h) -> UA/VB .z/.w
  for (int lh = 0; lh < 4; ++lh){
    const float* cw = caw + lh * 320;
    float av = wave_sum(accR * cw[lane]       + accA * cw[64 + lane]);
    float bv = wave_sum(accR * cw[192 + lane] + accA * cw[256 + lane]);
    if (lane == 0){
      float4* U = (lh < 2) ? UA0 : UA1;
      float4* V = (lh < 2) ? VB0 : VB1;
      ((float*)(U + w))[2 + (lh & 1)] = av;
      ((float*)(V + w))[2 + (lh & 1)] = bv;
    }
  }
  // layer-0 u/v: lane's float2 = relu(x0) cols (2*lane, 2*lane+1); half per head
  float rx = fmaxf(ax, 0.f), ry = fmaxf(ay, 0.f);
  int hl = lane >> 5;
  int cih = 2 * (lane - 32 * hl);
  const float* wv = eaw + hl * 192;
  float pu = half_sum(rx * wv[cih] + ry * wv[cih + 1]);
  float pv = half_sum(rx * wv[128 + cih] + ry * wv[128 + cih + 1]);
  if ((lane & 31) == 0){
    ((float*)(UA0 + w))[hl] = pu;
    ((float*)(VB0 + w))[hl] = pv;
  }
}

// layer-1 u/v tables from layer-0 output (out cols [0:128))
__global__ void k_uv1(const float* out, const float* eaw, float4* UA1, float4* VB1){
  int w = (blockIdx.x * blockDim.x + threadIdx.x) >> 6;
  int lane = threadIdx.x & 63;
  if (w >= NENT) return;
  float2 x = ((const float2*)(out + (size_t)w * 384))[lane];
  float rx = fmaxf(x.x, 0.f), ry = fmaxf(x.y, 0.f);
  int hl = lane >> 5;
  int cih = 2 * (lane - 32 * hl);
  const float* wv = eaw + 2 * 192 + hl * 192;
  float pu = half_sum(rx * wv[cih] + ry * wv[cih + 1]);
  float pv = half_sum(rx * wv[128 + cih] + ry * wv[128 + cih + 1]);
  if ((lane & 31) == 0){
    ((float*)(UA1 + w))[hl] = pu;
    ((float*)(VB1 + w))[hl] = pv;
  }
}

// fused edge scores + exp (no global max: exp(s)/Z identical math) + block sums
__global__ void k_se(const int* ee, const int* err,
                     const float4* UA, const float4* VB, const float4* HH,
                     const float* eab_l, const float* cab_l,
                     float* s0, float* s1, float* partials){
  int e = blockIdx.x * blockDim.x + threadIdx.x;
  int tid = threadIdx.x;
  __shared__ float sm[256];
  float ex0 = 0.f, ex1 = 0.f;
  if (e < EE){
    int row = ee[2 * e], col = ee[2 * e + 1];
    int r1 = err[2 * e], r2 = err[2 * e + 1];
    float4 ua = UA[row], vb = VB[col], h1 = HH[r1], h2 = HH[r2];
    float ea0 = ua.x + 0.5f * (h1.x + h2.x) + vb.x + eab_l[0];
    float ca0 = ua.z + 0.5f * (h1.z + h2.z) + vb.z + cab_l[0];
    ex0 = __expf(leaky(ea0) * leaky(ca0));
    s0[e] = ex0;
    float ea1 = ua.y + 0.5f * (h1.y + h2.y) + vb.y + eab_l[1];
    float ca1 = ua.w + 0.5f * (h1.w + h2.w) + vb.w + cab_l[1];
    ex1 = __expf(leaky(ea1) * leaky(ca1));
    s1[e] = ex1;
  }
  sm[tid] = ex0; __syncthreads();
  for (int s = 128; s; s >>= 1){
    if (tid < s) sm[tid] += sm[tid + s];
    __syncthreads();
  }
  if (tid == 0) partials[blockIdx.x] = sm[0];
  __syncthreads();
  sm[tid] = ex1; __syncthreads();
  for (int s = 128; s; s >>= 1){
    if (tid < s) sm[tid] += sm[tid + s];
    __syncthreads();
  }
  if (tid == 0) partials[PB + blockIdx.x] = sm[0];
}

// single-block finalize: Z per head
__global__ void k_final(const float* partials, float* scal, int nb){
  __shared__ float sm[1024];
  int tid = threadIdx.x;
  for (int h = 0; h < 2; ++h){
    float v = 0.f;
    for (int i = tid; i < nb; i += 1024) v += partials[h * PB + i];
    sm[tid] = v; __syncthreads();
    for (int s = 512; s; s >>= 1){
      if (tid < s) sm[tid] += sm[tid + s];
      __syncthreads();
    }
    if (tid == 0) scal[h] = sm[0];
    __syncthreads();
  }
}

// both heads in one wave: lanes 0-31 own head-0 cols (0..63), lanes 32-63 head-1.
// segment softmax over p = exp(s)/Z, then weighted neighbor sum, tanh.
__global__ void k_agg(const int* ee, const int* ptr, const float* s0, const float* s1,
                      const float* scal, const float* xsrc, float* outp, int ocol){
  int w = (blockIdx.x * blockDim.x + threadIdx.x) >> 6;
  int lane = threadIdx.x & 63;
  if (w >= NENT) return;
  int beg = ptr[w], end = ptr[w + 1];
  float invZ0 = 1.f / scal[0], invZ1 = 1.f / scal[1];
  float p0 = -INFINITY, p1 = -INFINITY;
  for (int e = beg + lane; e < end; e += 64){
    p0 = fmaxf(p0, s0[e] * invZ0);
    p1 = fmaxf(p1, s1[e] * invZ1);
  }
  float m0 = wave_max(p0), m1 = wave_max(p1);
  float z0 = 0.f, z1 = 0.f;
  for (int e = beg + lane; e < end; e += 64){
    z0 += __expf(s0[e] * invZ0 - m0);
    z1 += __expf(s1[e] * invZ1 - m1);
  }
  z0 = wave_sum(z0); z1 = wave_sum(z1);
  float iz0 = (z0 > 0.f) ? (1.f / z0) : 0.f;
  float iz1 = (z1 > 0.f) ? (1.f / z1) : 0.f;
  float ax = 0.f, ay = 0.f;
  for (int e0 = beg; e0 < end; e0 += 64){
    int e = e0 + lane;
    float w0 = 0.f, w1 = 0.f; int col = 0;
    if (e < end){
      col = ee[2 * e + 1];
      w0 = __expf(s0[e] * invZ0 - m0) * iz0;
      w1 = __expf(s1[e] * invZ1 - m1) * iz1;
    }
    int cnt = end - e0; if (cnt > 64) cnt = 64;
    for (int j = 0; j < cnt; ++j){
      float wj0 = __shfl(w0, j);
      float wj1 = __shfl(w1, j);
      int cj    = __shfl(col, j);
      float2 xv = ((const float2*)(xsrc + (size_t)cj * 384))[lane];
      float wsel = (lane < 32) ? wj0 : wj1;
      ax = fmaf(wsel, fmaxf(xv.x, 0.f), ax);
      ay = fmaf(wsel, fmaxf(xv.y, 0.f), ay);
    }
  }
  outp[(size_t)w * 384 + ocol + 2 * lane]     = tanhf(ax);
  outp[(size_t)w * 384 + ocol + 2 * lane + 1] = tanhf(ay);
}

extern "C" void kernel_launch(void* const* d_in, const int* in_sizes, int n_in,
                              void* d_out, int out_size, void* d_ws, size_t ws_size,
                              hipStream_t stream){
  const float* ent_emb  = (const float*)d_in[0];
  const float* rel_emb  = (const float*)d_in[1];
  const float* attr_emb = (const float*)d_in[2];
  const float* w_r      = (const float*)d_in[3];
  const float* b_r      = (const float*)d_in[4];
  const float* w_a      = (const float*)d_in[5];
  const float* b_a      = (const float*)d_in[6];
  const float* eaw      = (const float*)d_in[7];
  const float* eab      = (const float*)d_in[8];
  const float* caw      = (const float*)d_in[9];
  const float* cab      = (const float*)d_in[10];
  const int*   ee       = (const int*)d_in[11];
  const int*   er_rel   = (const int*)d_in[13];  // unused (er pairs per edge in er_index)
  const int*   er_idx   = (const int*)d_in[14];
  const int*   ea_idx   = (const int*)d_in[15];
  float* out = (float*)d_out;
  (void)er_rel;

  // workspace carve (~7.1 MB)
  int* pee = (int*)d_ws;                 // NENT+1
  int* per = pee + (NENT + 1);
  int* pea = per + (NENT + 1);
  float*  fbase = (float*)d_ws + 150004; // 16B-aligned (600016 % 16 == 0)
  float4* UA0 = (float4*)fbase;          // NENT each
  float4* VB0 = UA0 + NENT;
  float4* UA1 = VB0 + NENT;
  float4* VB1 = UA1 + NENT;
  float4* HH0 = VB1 + NENT;              // RREL each
  float4* HH1 = HH0 + RREL;
  float* s0      = (float*)(HH1 + RREL);
  float* s1      = s0 + EE;
  float* h_rel   = s1 + EE;
  float* h_attr  = h_rel + RREL;
  float* partials= h_attr + AATT;
  float* scal    = partials + 2 * PB;

  const int nb = (EE + 255) / 256;       // 1563 edge blocks
  const int gw = (NENT + 3) / 4;         // wave-per-entity grids

  k_ptr<<<(NENT + 1 + 255) / 256, 256, 0, stream>>>(ee, er_idx, ea_idx, pee, per, pea);
  k_small<<<(AATT + 255) / 256, 256, 0, stream>>>(rel_emb, attr_emb, w_r, w_a, eaw, caw,
                                                  h_rel, h_attr, HH0, HH1);
  k_phase1<<<gw, 256, 0, stream>>>(ent_emb, rel_emb, attr_emb, w_r, b_r, w_a, b_a,
                                   eaw, caw, er_idx, ea_idx, ee, per, pea, pee,
                                   h_rel, h_attr, UA0, VB0, UA1, VB1, out);
  // layer 0
  k_se<<<nb, 256, 0, stream>>>(ee, (const int*)d_in[13], UA0, VB0, HH0, eab, cab,
                               s0, s1, partials);
  k_final<<<1, 1024, 0, stream>>>(partials, scal, nb);
  k_agg<<<gw, 256, 0, stream>>>(ee, pee, s0, s1, scal, out + 128, out, 0);
  // layer 1
  k_uv1<<<gw, 256, 0, stream>>>(out, eaw, UA1, VB1);
  k_se<<<nb, 256, 0, stream>>>(ee, (const int*)d_in[13], UA1, VB1, HH1, eab + 2, cab + 2,
                               s0, s1, partials);
  k_final<<<1, 1024, 0, stream>>>(partials, scal, nb);
  k_agg<<<gw, 256, 0, stream>>>(ee, pee, s0, s1, scal, out, out, 128);
}

// Round 4
// 227.683 us; speedup vs baseline: 2.4116x; 1.3452x over previous
//
#include <hip/hip_runtime.h>
#include <math.h>

#define NENT 50000
#define RREL 2000
#define AATT 5000
#define EE   400000
#define E2   800000
#define EAE  400000
#define PB   2048   // partials stride per head

__device__ __forceinline__ float leaky(float v){ return v > 0.f ? v : 0.3f * v; }

__device__ __forceinline__ float wave_sum(float v){
#pragma unroll
  for (int m = 32; m; m >>= 1) v += __shfl_xor(v, m);
  return v;
}
__device__ __forceinline__ float wave_max(float v){
#pragma unroll
  for (int m = 32; m; m >>= 1) v = fmaxf(v, __shfl_xor(v, m));
  return v;
}
// reduces independently within each 32-lane half (xor masks < 32 never cross bit 5)
__device__ __forceinline__ float half_sum(float v){
#pragma unroll
  for (int m = 16; m; m >>= 1) v += __shfl_xor(v, m);
  return v;
}

__device__ int lowb(const int* a, int n, int key){
  int lo = 0, hi = n;
  while (lo < hi){ int mid = (lo + hi) >> 1; if (a[2 * mid] < key) lo = mid + 1; else hi = mid; }
  return lo;
}

__global__ void k_ptr(const int* ee, const int* er, const int* ea,
                      int* pee, int* per, int* pea){
  int i = blockIdx.x * blockDim.x + threadIdx.x;
  if (i > NENT) return;
  pee[i] = lowb(ee, EE, i);
  per[i] = lowb(er, E2, i);
  pea[i] = lowb(ea, EAE, i);
}

// per-relation/attr scalar tables; HH_l[r] = (hr_h0, hr_h1, hc_h0, hc_h1)
__global__ void k_small(const float* rel_emb, const float* attr_emb,
                        const float* w_r, const float* w_a,
                        const float* eaw, const float* caw,
                        float* h_rel, float* h_attr, float4* HH0, float4* HH1){
  int t = blockIdx.x * blockDim.x + threadIdx.x;
  if (t < RREL){
    const float* e = rel_emb + (size_t)t * 64;
    float s = 0.f;
    for (int k = 0; k < 64; ++k) s += e[k] * w_r[128 + k];
    h_rel[t] = s;
    float hr[4], hc[4];
    for (int lh = 0; lh < 4; ++lh){
      float a = 0.f, c = 0.f;
      for (int k = 0; k < 64; ++k){
        a += e[k] * eaw[lh * 192 + 64 + k];
        c += e[k] * caw[lh * 320 + 128 + k];
      }
      hr[lh] = a; hc[lh] = c;
    }
    HH0[t] = make_float4(hr[0], hr[1], hc[0], hc[1]);
    HH1[t] = make_float4(hr[2], hr[3], hc[2], hc[3]);
  }
  if (t < AATT){
    const float* e = attr_emb + (size_t)t * 64;
    float s = 0.f;
    for (int k = 0; k < 64; ++k) s += e[k] * w_a[128 + k];
    h_attr[t] = s;
  }
}

// GAT concept aggregation: online max+sum in ONE gather pass (chunk-0 cached in
// registers), then unroll-4 shfl-broadcast weighted row gather.
__device__ float concept_agg(float he, const float* h_tab, const int* idx,
                             int beg, int end, const float* emb, int lane){
  int e = beg + lane;
  int obj0 = 0;
  float v0 = -INFINITY;
  if (e < end){
    obj0 = ((const int2*)idx)[e].y;
    v0 = leaky(he + h_tab[obj0]);
  }
  float m = v0;
  float t = (e < end) ? 1.f : 0.f;
  for (int e2 = e + 64; e2 < end; e2 += 64){
    float v = leaky(he + h_tab[((const int2*)idx)[e2].y]);
    float mn = fmaxf(m, v);
    t = t * __expf(m - mn) + __expf(v - mn);
    m = mn;
  }
  float M = wave_max(m);
  float z = wave_sum((t > 0.f) ? t * __expf(m - M) : 0.f);
  float invz = (z > 0.f) ? (1.f / z) : 0.f;
  float acc = 0.f;
  for (int e0 = beg; e0 < end; e0 += 64){
    int e1 = e0 + lane;
    float wgt = 0.f; int obj = 0;
    if (e1 < end){
      if (e0 == beg){ obj = obj0; wgt = __expf(v0 - M) * invz; }
      else {
        obj = ((const int2*)idx)[e1].y;
        wgt = __expf(leaky(he + h_tab[obj]) - M) * invz;
      }
    }
    int cnt = end - e0; if (cnt > 64) cnt = 64;
    int j = 0;
    for (; j + 4 <= cnt; j += 4){
      int o0 = __shfl(obj, j),   o1 = __shfl(obj, j+1),
          o2 = __shfl(obj, j+2), o3 = __shfl(obj, j+3);
      float w0 = __shfl(wgt, j),   w1 = __shfl(wgt, j+1),
            w2 = __shfl(wgt, j+2), w3 = __shfl(wgt, j+3);
      float f0 = emb[(size_t)o0 * 64 + lane];
      float f1 = emb[(size_t)o1 * 64 + lane];
      float f2 = emb[(size_t)o2 * 64 + lane];
      float f3 = emb[(size_t)o3 * 64 + lane];
      acc = fmaf(w0, f0, acc); acc = fmaf(w1, f1, acc);
      acc = fmaf(w2, f2, acc); acc = fmaf(w3, f3, acc);
    }
    for (; j < cnt; ++j){
      float wj = __shfl(wgt, j);
      int oj   = __shfl(obj, j);
      acc = fmaf(wj, emb[(size_t)oj * 64 + lane], acc);
    }
  }
  return fmaxf(acc, 0.f);
}

// all row-local per-entity work fused: ent dot tables, both concept GATs,
// mean aggregation, con-attention A/B tables (4 lh), layer-0 u/v tables.
__global__ void k_phase1(const float* ent_emb, const float* rel_emb, const float* attr_emb,
                         const float* w_r, const float* b_r, const float* w_a, const float* b_a,
                         const float* eaw, const float* caw,
                         const int* er_idx, const int* ea_idx, const int* ee,
                         const int* per, const int* pea, const int* pee,
                         const float* h_rel, const float* h_attr,
                         float4* UA0, float4* VB0, float4* UA1, float4* VB1,
                         float* out){
  int w = (blockIdx.x * blockDim.x + threadIdx.x) >> 6;
  int lane = threadIdx.x & 63;
  if (w >= NENT) return;
  // her / hea (dot of own ent row with w_r/w_a first 128)
  float2 v = ((const float2*)(ent_emb + (size_t)w * 128))[lane];
  float2 a = ((const float2*)w_r)[lane];
  float2 b = ((const float2*)w_a)[lane];
  float her = wave_sum(v.x * a.x + v.y * a.y);
  float hea = wave_sum(v.x * b.x + v.y * b.y);
  // concept aggregations
  float accR = concept_agg(her + b_r[0], h_rel, er_idx, per[w], per[w + 1], rel_emb, lane);
  float accA = concept_agg(hea + b_a[0], h_attr, ea_idx, pea[w], pea[w + 1], attr_emb, lane);
  out[(size_t)w * 384 + 256 + lane] = accR;
  out[(size_t)w * 384 + 320 + lane] = accA;
  out[(size_t)NENT * 384 + (size_t)w * 128 + lane] = accR;
  out[(size_t)NENT * 384 + (size_t)w * 128 + 64 + lane] = accA;
  // mean neighbor aggregation -> x0 (out cols [128:256)), unroll-4 gather
  int beg = pee[w], end = pee[w + 1];
  float ax = 0.f, ay = 0.f;
  for (int e0 = beg; e0 < end; e0 += 64){
    int e1 = e0 + lane;
    int col = (e1 < end) ? ((const int2*)ee)[e1].y : 0;
    int cnt = end - e0; if (cnt > 64) cnt = 64;
    int j = 0;
    for (; j + 4 <= cnt; j += 4){
      int c0 = __shfl(col, j),   c1 = __shfl(col, j+1),
          c2 = __shfl(col, j+2), c3 = __shfl(col, j+3);
      float2 v0 = ((const float2*)(ent_emb + (size_t)c0 * 128))[lane];
      float2 v1 = ((const float2*)(ent_emb + (size_t)c1 * 128))[lane];
      float2 v2 = ((const float2*)(ent_emb + (size_t)c2 * 128))[lane];
      float2 v3 = ((const float2*)(ent_emb + (size_t)c3 * 128))[lane];
      ax += v0.x + v1.x + v2.x + v3.x;
      ay += v0.y + v1.y + v2.y + v3.y;
    }
    for (; j < cnt; ++j){
      int cj = __shfl(col, j);
      float2 vv = ((const float2*)(ent_emb + (size_t)cj * 128))[lane];
      ax += vv.x; ay += vv.y;
    }
  }
  float invd = 1.f / fmaxf((float)(end - beg), 1.f);
  ax *= invd; ay *= invd;
  out[(size_t)w * 384 + 128 + 2 * lane]     = ax;
  out[(size_t)w * 384 + 128 + 2 * lane + 1] = ay;
  // con-attention tables A (row) / B (col) for all 4 (l,h) -> UA/VB .z/.w
  for (int lh = 0; lh < 4; ++lh){
    const float* cw = caw + lh * 320;
    float av = wave_sum(accR * cw[lane]       + accA * cw[64 + lane]);
    float bv = wave_sum(accR * cw[192 + lane] + accA * cw[256 + lane]);
    if (lane == 0){
      float4* U = (lh < 2) ? UA0 : UA1;
      float4* V = (lh < 2) ? VB0 : VB1;
      ((float*)(U + w))[2 + (lh & 1)] = av;
      ((float*)(V + w))[2 + (lh & 1)] = bv;
    }
  }
  // layer-0 u/v: lane's float2 = relu(x0) cols (2*lane, 2*lane+1); half per head
  float rx = fmaxf(ax, 0.f), ry = fmaxf(ay, 0.f);
  int hl = lane >> 5;
  int cih = 2 * (lane - 32 * hl);
  const float* wv = eaw + hl * 192;
  float pu = half_sum(rx * wv[cih] + ry * wv[cih + 1]);
  float pv = half_sum(rx * wv[128 + cih] + ry * wv[128 + cih + 1]);
  if ((lane & 31) == 0){
    ((float*)(UA0 + w))[hl] = pu;
    ((float*)(VB0 + w))[hl] = pv;
  }
}

// fused edge scores + exp (no global max: exp(s)/Z identical math) + block sums
__global__ void k_se(const int* ee, const int* err,
                     const float4* UA, const float4* VB, const float4* HH,
                     const float* eab_l, const float* cab_l,
                     float* s0, float* s1, float* partials){
  int e = blockIdx.x * blockDim.x + threadIdx.x;
  int tid = threadIdx.x;
  __shared__ float sm[256];
  float ex0 = 0.f, ex1 = 0.f;
  if (e < EE){
    int2 rc = ((const int2*)ee)[e];
    int2 rr = ((const int2*)err)[e];
    float4 ua = UA[rc.x], vb = VB[rc.y], h1 = HH[rr.x], h2 = HH[rr.y];
    float ea0 = ua.x + 0.5f * (h1.x + h2.x) + vb.x + eab_l[0];
    float ca0 = ua.z + 0.5f * (h1.z + h2.z) + vb.z + cab_l[0];
    ex0 = __expf(leaky(ea0) * leaky(ca0));
    s0[e] = ex0;
    float ea1 = ua.y + 0.5f * (h1.y + h2.y) + vb.y + eab_l[1];
    float ca1 = ua.w + 0.5f * (h1.w + h2.w) + vb.w + cab_l[1];
    ex1 = __expf(leaky(ea1) * leaky(ca1));
    s1[e] = ex1;
  }
  sm[tid] = ex0; __syncthreads();
  for (int s = 128; s; s >>= 1){
    if (tid < s) sm[tid] += sm[tid + s];
    __syncthreads();
  }
  if (tid == 0) partials[blockIdx.x] = sm[0];
  __syncthreads();
  sm[tid] = ex1; __syncthreads();
  for (int s = 128; s; s >>= 1){
    if (tid < s) sm[tid] += sm[tid + s];
    __syncthreads();
  }
  if (tid == 0) partials[PB + blockIdx.x] = sm[0];
}

// single-block finalize: Z per head
__global__ void k_final(const float* partials, float* scal, int nb){
  __shared__ float sm[1024];
  int tid = threadIdx.x;
  for (int h = 0; h < 2; ++h){
    float v = 0.f;
    for (int i = tid; i < nb; i += 1024) v += partials[h * PB + i];
    sm[tid] = v; __syncthreads();
    for (int s = 512; s; s >>= 1){
      if (tid < s) sm[tid] += sm[tid + s];
      __syncthreads();
    }
    if (tid == 0) scal[h] = sm[0];
    __syncthreads();
  }
}

// both heads in one wave: lanes 0-31 own head-0 cols, lanes 32-63 head-1.
// Online segment softmax (1 pass over s, chunk-0 cached), unroll-4 PV gather,
// tanh, and optionally fused u/v tables for the NEXT layer.
__global__ void k_agg(const int* ee, const int* ptr, const float* s0, const float* s1,
                      const float* scal, const float* xsrc, float* outp, int ocol,
                      const float* eaw_next, float4* UAn, float4* VBn){
  int w = (blockIdx.x * blockDim.x + threadIdx.x) >> 6;
  int lane = threadIdx.x & 63;
  if (w >= NENT) return;
  int beg = ptr[w], end = ptr[w + 1];
  float invZ0 = 1.f / scal[0], invZ1 = 1.f / scal[1];
  int e = beg + lane;
  float c0 = -INFINITY, c1 = -INFINITY;
  int col0 = 0;
  if (e < end){
    c0 = s0[e] * invZ0;
    c1 = s1[e] * invZ1;
    col0 = ((const int2*)ee)[e].y;
  }
  float m0 = c0, m1 = c1;
  float t0 = (e < end) ? 1.f : 0.f, t1 = t0;
  for (int e2 = e + 64; e2 < end; e2 += 64){
    float p0 = s0[e2] * invZ0, p1 = s1[e2] * invZ1;
    float n0 = fmaxf(m0, p0); t0 = t0 * __expf(m0 - n0) + __expf(p0 - n0); m0 = n0;
    float n1 = fmaxf(m1, p1); t1 = t1 * __expf(m1 - n1) + __expf(p1 - n1); m1 = n1;
  }
  float M0 = wave_max(m0), M1 = wave_max(m1);
  float z0 = wave_sum((t0 > 0.f) ? t0 * __expf(m0 - M0) : 0.f);
  float z1 = wave_sum((t1 > 0.f) ? t1 * __expf(m1 - M1) : 0.f);
  float iz0 = (z0 > 0.f) ? (1.f / z0) : 0.f;
  float iz1 = (z1 > 0.f) ? (1.f / z1) : 0.f;
  float ax = 0.f, ay = 0.f;
  for (int e0 = beg; e0 < end; e0 += 64){
    int e1 = e0 + lane;
    float w0 = 0.f, w1 = 0.f; int col = 0;
    if (e1 < end){
      if (e0 == beg){
        col = col0;
        w0 = __expf(c0 - M0) * iz0;
        w1 = __expf(c1 - M1) * iz1;
      } else {
        col = ((const int2*)ee)[e1].y;
        w0 = __expf(s0[e1] * invZ0 - M0) * iz0;
        w1 = __expf(s1[e1] * invZ1 - M1) * iz1;
      }
    }
    int cnt = end - e0; if (cnt > 64) cnt = 64;
    int j = 0;
    for (; j + 4 <= cnt; j += 4){
      int cA = __shfl(col, j),   cB = __shfl(col, j+1),
          cC = __shfl(col, j+2), cD = __shfl(col, j+3);
      float a0 = __shfl(w0, j),   a1 = __shfl(w0, j+1),
            a2 = __shfl(w0, j+2), a3 = __shfl(w0, j+3);
      float b0 = __shfl(w1, j),   b1 = __shfl(w1, j+1),
            b2 = __shfl(w1, j+2), b3 = __shfl(w1, j+3);
      float2 vA = ((const float2*)(xsrc + (size_t)cA * 384))[lane];
      float2 vB = ((const float2*)(xsrc + (size_t)cB * 384))[lane];
      float2 vC = ((const float2*)(xsrc + (size_t)cC * 384))[lane];
      float2 vD = ((const float2*)(xsrc + (size_t)cD * 384))[lane];
      float sA = (lane < 32) ? a0 : b0;
      float sB = (lane < 32) ? a1 : b1;
      float sC = (lane < 32) ? a2 : b2;
      float sD = (lane < 32) ? a3 : b3;
      ax = fmaf(sA, fmaxf(vA.x, 0.f), ax); ay = fmaf(sA, fmaxf(vA.y, 0.f), ay);
      ax = fmaf(sB, fmaxf(vB.x, 0.f), ax); ay = fmaf(sB, fmaxf(vB.y, 0.f), ay);
      ax = fmaf(sC, fmaxf(vC.x, 0.f), ax); ay = fmaf(sC, fmaxf(vC.y, 0.f), ay);
      ax = fmaf(sD, fmaxf(vD.x, 0.f), ax); ay = fmaf(sD, fmaxf(vD.y, 0.f), ay);
    }
    for (; j < cnt; ++j){
      float wj0 = __shfl(w0, j);
      float wj1 = __shfl(w1, j);
      int cj    = __shfl(col, j);
      float2 xv = ((const float2*)(xsrc + (size_t)cj * 384))[lane];
      float wsel = (lane < 32) ? wj0 : wj1;
      ax = fmaf(wsel, fmaxf(xv.x, 0.f), ax);
      ay = fmaf(wsel, fmaxf(xv.y, 0.f), ay);
    }
  }
  float tx = tanhf(ax), ty = tanhf(ay);
  outp[(size_t)w * 384 + ocol + 2 * lane]     = tx;
  outp[(size_t)w * 384 + ocol + 2 * lane + 1] = ty;
  if (eaw_next){
    // fused u/v tables for next layer (this lane owns exactly cols 2lane,2lane+1)
    float rx = fmaxf(tx, 0.f), ry = fmaxf(ty, 0.f);
    int hl = lane >> 5;
    int cih = 2 * (lane - 32 * hl);
    const float* wv = eaw_next + hl * 192;
    float pu = half_sum(rx * wv[cih] + ry * wv[cih + 1]);
    float pv = half_sum(rx * wv[128 + cih] + ry * wv[128 + cih + 1]);
    if ((lane & 31) == 0){
      ((float*)(UAn + w))[hl] = pu;
      ((float*)(VBn + w))[hl] = pv;
    }
  }
}

extern "C" void kernel_launch(void* const* d_in, const int* in_sizes, int n_in,
                              void* d_out, int out_size, void* d_ws, size_t ws_size,
                              hipStream_t stream){
  const float* ent_emb  = (const float*)d_in[0];
  const float* rel_emb  = (const float*)d_in[1];
  const float* attr_emb = (const float*)d_in[2];
  const float* w_r      = (const float*)d_in[3];
  const float* b_r      = (const float*)d_in[4];
  const float* w_a      = (const float*)d_in[5];
  const float* b_a      = (const float*)d_in[6];
  const float* eaw      = (const float*)d_in[7];
  const float* eab      = (const float*)d_in[8];
  const float* caw      = (const float*)d_in[9];
  const float* cab      = (const float*)d_in[10];
  const int*   ee       = (const int*)d_in[11];
  const int*   er_rel2  = (const int*)d_in[13];  // per-ee-edge relation pair (E2)
  const int*   er_idx   = (const int*)d_in[14];
  const int*   ea_idx   = (const int*)d_in[15];
  float* out = (float*)d_out;

  // workspace carve (~7.1 MB)
  int* pee = (int*)d_ws;                 // NENT+1
  int* per = pee + (NENT + 1);
  int* pea = per + (NENT + 1);
  float*  fbase = (float*)d_ws + 150004; // 16B-aligned (600016 % 16 == 0)
  float4* UA0 = (float4*)fbase;          // NENT each
  float4* VB0 = UA0 + NENT;
  float4* UA1 = VB0 + NENT;
  float4* VB1 = UA1 + NENT;
  float4* HH0 = VB1 + NENT;              // RREL each
  float4* HH1 = HH0 + RREL;
  float* s0      = (float*)(HH1 + RREL);
  float* s1      = s0 + EE;
  float* h_rel   = s1 + EE;
  float* h_attr  = h_rel + RREL;
  float* partials= h_attr + AATT;
  float* scal    = partials + 2 * PB;

  const int nb = (EE + 255) / 256;       // 1563 edge blocks
  const int gw = (NENT + 3) / 4;         // wave-per-entity grids

  k_ptr<<<(NENT + 1 + 255) / 256, 256, 0, stream>>>(ee, er_idx, ea_idx, pee, per, pea);
  k_small<<<(AATT + 255) / 256, 256, 0, stream>>>(rel_emb, attr_emb, w_r, w_a, eaw, caw,
                                                  h_rel, h_attr, HH0, HH1);
  k_phase1<<<gw, 256, 0, stream>>>(ent_emb, rel_emb, attr_emb, w_r, b_r, w_a, b_a,
                                   eaw, caw, er_idx, ea_idx, ee, per, pea, pee,
                                   h_rel, h_attr, UA0, VB0, UA1, VB1, out);
  // layer 0
  k_se<<<nb, 256, 0, stream>>>(ee, er_rel2, UA0, VB0, HH0, eab, cab, s0, s1, partials);
  k_final<<<1, 1024, 0, stream>>>(partials, scal, nb);
  k_agg<<<gw, 256, 0, stream>>>(ee, pee, s0, s1, scal, out + 128, out, 0,
                                eaw + 2 * 192, UA1, VB1);
  // layer 1
  k_se<<<nb, 256, 0, stream>>>(ee, er_rel2, UA1, VB1, HH1, eab + 2, cab + 2, s0, s1, partials);
  k_final<<<1, 1024, 0, stream>>>(partials, scal, nb);
  k_agg<<<gw, 256, 0, stream>>>(ee, pee, s0, s1, scal, out, out, 128,
                                (const float*)nullptr, (float4*)nullptr, (float4*)nullptr);
}